// Round 5
// baseline (2373.808 us; speedup 1.0000x reference)
//
#include <hip/hip_runtime.h>

#define TT 2048

typedef _Float16 f16;
typedef _Float16 f16x2 __attribute__((ext_vector_type(2)));
typedef unsigned int u32;

static __device__ __forceinline__ float fdot2f(u32 a, u32 b, float c) {
  return __builtin_amdgcn_fdot2(__builtin_bit_cast(f16x2, a),
                                __builtin_bit_cast(f16x2, b), c, false);
}
static __device__ __forceinline__ u32 packh2(float a, float b) {
  f16x2 v; v[0] = (f16)a; v[1] = (f16)b;
  return __builtin_bit_cast(u32, v);
}
static __device__ __forceinline__ float sigm(float x) {
  return 1.f / (1.f + __expf(-x));
}
static __device__ __forceinline__ float tanh_(float x) {
  x = fminf(15.f, fmaxf(-15.f, x));
  const float e = __expf(2.f * x);
  return (e - 1.f) / (e + 1.f);
}

// 3 specialized waves per row (structure identical to R4). ONLY change:
// __launch_bounds__(192, 1) instead of (192, 2). The old bound capped VGPRs
// at 128 == exactly the w[4][32] array, so the compiler rematerialized the
// weights by RE-LOADING them from global memory every iteration (~200cyc L2
// chains + vmcnt drain at each barrier == the observed ~2400 cyc/iter).
// Cap 256 lets weights truly live in VGPRs (~175 used).
__launch_bounds__(192, 1)
__global__ void lstm2_pc3_kernel(const float* __restrict__ x1,
                                 const float* __restrict__ x2,
                                 const float* __restrict__ Wih1,
                                 const float* __restrict__ Whh1,
                                 const float* __restrict__ bih1,
                                 const float* __restrict__ bhh1,
                                 const float* __restrict__ Wih2,
                                 const float* __restrict__ Whh2,
                                 const float* __restrict__ bih2,
                                 const float* __restrict__ bhh2,
                                 float* __restrict__ out)
{
  __shared__ u32 s_xbig[8][32];    // x ring: slot t&7 holds x[t] as f16 pairs
  __shared__ u32 s_h1[2][32];      // h1 double buffer, f16 pairs
  __shared__ u32 s_h2[16];         // h2, f16 pairs (wave2-private)
  __shared__ float s_pre[4][256];  // pre1 ring, f32

  const int tid = threadIdx.x;
  const int lane = tid & 63;
  const int wid = tid >> 6;
  const int bid = blockIdx.x;
  const int which = bid >> 8;      // 0 -> x1, 1 -> x2
  const int row = bid & 255;
  const float* __restrict__ xg = (which ? x2 : x1) + row * (TT * 64) + lane;

  u32 w[4][32];
  float bias[4] = {0.f, 0.f, 0.f, 0.f};

  if (wid == 0) {
    #pragma unroll
    for (int g = 0; g < 4; ++g) {
      const float* src = Wih1 + (lane + 64 * g) * 64;
      #pragma unroll
      for (int kp = 0; kp < 32; ++kp) {
        const float2 v = *(const float2*)(src + 2 * kp);
        w[g][kp] = packh2(v.x, v.y);
      }
      bias[g] = bih1[lane + 64 * g] + bhh1[lane + 64 * g];
    }
  } else if (wid == 1) {
    #pragma unroll
    for (int g = 0; g < 4; ++g) {
      const float* src = Whh1 + (lane + 64 * g) * 64;
      #pragma unroll
      for (int kp = 0; kp < 32; ++kp) {
        const float2 v = *(const float2*)(src + 2 * kp);
        w[g][kp] = packh2(v.x, v.y);
      }
    }
    if (lane < 32) s_h1[1][lane] = 0u;   // h1[-1] in slot (-1)&1 == 1
  } else {
    #pragma unroll
    for (int g = 0; g < 2; ++g) {
      const float* src = Wih2 + (lane + 64 * g) * 64;
      #pragma unroll
      for (int kp = 0; kp < 32; ++kp) {
        const float2 v = *(const float2*)(src + 2 * kp);
        w[g][kp] = packh2(v.x, v.y);
      }
      const float* s2 = Whh2 + (lane + 64 * g) * 32;
      #pragma unroll
      for (int kp = 0; kp < 16; ++kp) {
        const float2 v = *(const float2*)(s2 + 2 * kp);
        w[2 + g][kp] = packh2(v.x, v.y);
      }
      #pragma unroll
      for (int kp = 16; kp < 32; ++kp) w[2 + g][kp] = 0u;
      bias[g] = bih2[lane + 64 * g] + bhh2[lane + 64 * g];
    }
    if (lane < 16) s_h2[lane] = 0u;
  }

  float c1 = 0.f, c2 = 0.f;
  // 8 named prefetch registers (static indices only -> stay in VGPRs)
  float xr0 = 0.f, xr1 = 0.f, xr2 = 0.f, xr3 = 0.f;
  float xr4 = 0.f, xr5 = 0.f, xr6 = 0.f, xr7 = 0.f;

  // ---- prologue (waveP): x[0],x[1] -> slots 0,1; pre[0],pre[1]; prime xr ----
  if (wid == 0) {
    ((f16*)s_xbig[0])[lane] = (f16)xg[0];
    ((f16*)s_xbig[1])[lane] = (f16)xg[64];
    #pragma unroll
    for (int p = 0; p < 2; ++p) {
      float a0 = bias[0], a1 = bias[1], a2 = bias[2], a3 = bias[3];
      const u32* xp = s_xbig[p];
      #pragma unroll
      for (int q = 0; q < 8; ++q) {
        const uint4 xv = *(const uint4*)&xp[4 * q];
        a0 = fdot2f(w[0][4*q+0], xv.x, a0); a1 = fdot2f(w[1][4*q+0], xv.x, a1);
        a2 = fdot2f(w[2][4*q+0], xv.x, a2); a3 = fdot2f(w[3][4*q+0], xv.x, a3);
        a0 = fdot2f(w[0][4*q+1], xv.y, a0); a1 = fdot2f(w[1][4*q+1], xv.y, a1);
        a2 = fdot2f(w[2][4*q+1], xv.y, a2); a3 = fdot2f(w[3][4*q+1], xv.y, a3);
        a0 = fdot2f(w[0][4*q+2], xv.z, a0); a1 = fdot2f(w[1][4*q+2], xv.z, a1);
        a2 = fdot2f(w[2][4*q+2], xv.z, a2); a3 = fdot2f(w[3][4*q+2], xv.z, a3);
        a0 = fdot2f(w[0][4*q+3], xv.w, a0); a1 = fdot2f(w[1][4*q+3], xv.w, a1);
        a2 = fdot2f(w[2][4*q+3], xv.w, a2); a3 = fdot2f(w[3][4*q+3], xv.w, a3);
      }
      s_pre[p][lane]       = a0;
      s_pre[p][lane + 64]  = a1;
      s_pre[p][lane + 128] = a2;
      s_pre[p][lane + 192] = a3;
    }
    // prime xr = x[2..9] (committed at iter 0)
    xr0 = xg[2 * 64]; xr1 = xg[3 * 64]; xr2 = xg[4 * 64]; xr3 = xg[5 * 64];
    xr4 = xg[6 * 64]; xr5 = xg[7 * 64]; xr6 = xg[8 * 64]; xr7 = xg[9 * 64];
  }
  __syncthreads();

  #pragma unroll 1
  for (int i = 0; i <= TT; ++i) {
    if (wid == 0) {
      if ((i & 7) == 0) {
        // commit xr (= x[i+2 .. i+9]) to ring slots (t & 7)
        ((f16*)s_xbig[(i + 2) & 7])[lane] = (f16)xr0;
        ((f16*)s_xbig[(i + 3) & 7])[lane] = (f16)xr1;
        ((f16*)s_xbig[(i + 4) & 7])[lane] = (f16)xr2;
        ((f16*)s_xbig[(i + 5) & 7])[lane] = (f16)xr3;
        ((f16*)s_xbig[(i + 6) & 7])[lane] = (f16)xr4;
        ((f16*)s_xbig[(i + 7) & 7])[lane] = (f16)xr5;
        ((f16*)s_xbig[(i + 8) & 7])[lane] = (f16)xr6;
        ((f16*)s_xbig[(i + 9) & 7])[lane] = (f16)xr7;
        // issue next batch x[i+10 .. i+17] (clamped; clamped values unused)
        const int tm = TT - 1;
        xr0 = xg[(i + 10 < TT ? i + 10 : tm) * 64];
        xr1 = xg[(i + 11 < TT ? i + 11 : tm) * 64];
        xr2 = xg[(i + 12 < TT ? i + 12 : tm) * 64];
        xr3 = xg[(i + 13 < TT ? i + 13 : tm) * 64];
        xr4 = xg[(i + 14 < TT ? i + 14 : tm) * 64];
        xr5 = xg[(i + 15 < TT ? i + 15 : tm) * 64];
        xr6 = xg[(i + 16 < TT ? i + 16 : tm) * 64];
        xr7 = xg[(i + 17 < TT ? i + 17 : tm) * 64];
      }
      if (i + 2 < TT) {
        float a0 = bias[0], a1 = bias[1], a2 = bias[2], a3 = bias[3];
        const u32* xp = s_xbig[(i + 2) & 7];
        #pragma unroll
        for (int q = 0; q < 8; ++q) {
          const uint4 xv = *(const uint4*)&xp[4 * q];
          a0 = fdot2f(w[0][4*q+0], xv.x, a0); a1 = fdot2f(w[1][4*q+0], xv.x, a1);
          a2 = fdot2f(w[2][4*q+0], xv.x, a2); a3 = fdot2f(w[3][4*q+0], xv.x, a3);
          a0 = fdot2f(w[0][4*q+1], xv.y, a0); a1 = fdot2f(w[1][4*q+1], xv.y, a1);
          a2 = fdot2f(w[2][4*q+1], xv.y, a2); a3 = fdot2f(w[3][4*q+1], xv.y, a3);
          a0 = fdot2f(w[0][4*q+2], xv.z, a0); a1 = fdot2f(w[1][4*q+2], xv.z, a1);
          a2 = fdot2f(w[2][4*q+2], xv.z, a2); a3 = fdot2f(w[3][4*q+2], xv.z, a3);
          a0 = fdot2f(w[0][4*q+3], xv.w, a0); a1 = fdot2f(w[1][4*q+3], xv.w, a1);
          a2 = fdot2f(w[2][4*q+3], xv.w, a2); a3 = fdot2f(w[3][4*q+3], xv.w, a3);
        }
        const int sl = (i + 2) & 3;
        s_pre[sl][lane]       = a0;
        s_pre[sl][lane + 64]  = a1;
        s_pre[sl][lane + 128] = a2;
        s_pre[sl][lane + 192] = a3;
      }
    } else if (wid == 1) {
      // layer-1 step i: even/odd-split accumulators (8 chains of 16)
      if (i < TT) {
        const float* pr = s_pre[i & 3];
        float a0 = pr[lane], a1 = pr[lane + 64];
        float a2 = pr[lane + 128], a3 = pr[lane + 192];
        float e0 = 0.f, e1 = 0.f, e2 = 0.f, e3 = 0.f;
        const u32* hp = s_h1[(i + 1) & 1];          // h1[i-1]
        #pragma unroll
        for (int q = 0; q < 8; ++q) {
          const uint4 hv = *(const uint4*)&hp[4 * q];
          a0 = fdot2f(w[0][4*q+0], hv.x, a0); e0 = fdot2f(w[0][4*q+1], hv.y, e0);
          a1 = fdot2f(w[1][4*q+0], hv.x, a1); e1 = fdot2f(w[1][4*q+1], hv.y, e1);
          a2 = fdot2f(w[2][4*q+0], hv.x, a2); e2 = fdot2f(w[2][4*q+1], hv.y, e2);
          a3 = fdot2f(w[3][4*q+0], hv.x, a3); e3 = fdot2f(w[3][4*q+1], hv.y, e3);
          a0 = fdot2f(w[0][4*q+2], hv.z, a0); e0 = fdot2f(w[0][4*q+3], hv.w, e0);
          a1 = fdot2f(w[1][4*q+2], hv.z, a1); e1 = fdot2f(w[1][4*q+3], hv.w, e1);
          a2 = fdot2f(w[2][4*q+2], hv.z, a2); e2 = fdot2f(w[2][4*q+3], hv.w, e2);
          a3 = fdot2f(w[3][4*q+2], hv.z, a3); e3 = fdot2f(w[3][4*q+3], hv.w, e3);
        }
        a0 += e0; a1 += e1; a2 += e2; a3 += e3;
        const float i1 = sigm(a0), f1 = sigm(a1), g1 = tanh_(a2), o1 = sigm(a3);
        c1 = f1 * c1 + i1 * g1;
        const float h1v = o1 * tanh_(c1);
        ((f16*)s_h1[i & 1])[lane] = (f16)h1v;
      }
    } else {
      // layer-2, one step behind: t = i-1
      if (i > 0) {
        const int t = i - 1;
        float b0 = bias[0], b1_ = bias[1];
        float e0 = 0.f, e1 = 0.f;
        const u32* hp = s_h1[t & 1];                // h1[t]
        #pragma unroll
        for (int q = 0; q < 8; ++q) {
          const uint4 hv = *(const uint4*)&hp[4 * q];
          b0 = fdot2f(w[0][4*q+0], hv.x, b0); e0 = fdot2f(w[0][4*q+1], hv.y, e0);
          b1_ = fdot2f(w[1][4*q+0], hv.x, b1_); e1 = fdot2f(w[1][4*q+1], hv.y, e1);
          b0 = fdot2f(w[0][4*q+2], hv.z, b0); e0 = fdot2f(w[0][4*q+3], hv.w, e0);
          b1_ = fdot2f(w[1][4*q+2], hv.z, b1_); e1 = fdot2f(w[1][4*q+3], hv.w, e1);
        }
        #pragma unroll
        for (int q = 0; q < 4; ++q) {
          const uint4 hv = *(const uint4*)&s_h2[4 * q];   // h2[t-1]
          b0 = fdot2f(w[2][4*q+0], hv.x, b0); e0 = fdot2f(w[2][4*q+1], hv.y, e0);
          b1_ = fdot2f(w[3][4*q+0], hv.x, b1_); e1 = fdot2f(w[3][4*q+1], hv.y, e1);
          b0 = fdot2f(w[2][4*q+2], hv.z, b0); e0 = fdot2f(w[2][4*q+3], hv.w, e0);
          b1_ = fdot2f(w[3][4*q+2], hv.z, b1_); e1 = fdot2f(w[3][4*q+3], hv.w, e1);
        }
        b0 += e0; b1_ += e1;
        const float p0 = __shfl_xor(b0, 32, 64);
        const float p1 = __shfl_xor(b1_, 32, 64);
        const bool lo = lane < 32;
        const float gi = lo ? b0  : p0;
        const float gf = lo ? p0  : b0;
        const float gg = lo ? b1_ : p1;
        const float go = lo ? p1  : b1_;
        const float i2 = sigm(gi), f2 = sigm(gf), g2v = tanh_(gg), o2 = sigm(go);
        c2 = f2 * c2 + i2 * g2v;
        const float h2v = o2 * tanh_(c2);
        if (lo) ((f16*)s_h2)[lane] = (f16)h2v;
        if (t == TT - 1 && lo) out[which * 8192 + row * 32 + lane] = h2v;
      }
    }
    __syncthreads();
  }
}

extern "C" void kernel_launch(void* const* d_in, const int* in_sizes, int n_in,
                              void* d_out, int out_size, void* d_ws, size_t ws_size,
                              hipStream_t stream) {
  const float* x1   = (const float*)d_in[0];
  const float* x2   = (const float*)d_in[1];
  const float* Wih1 = (const float*)d_in[2];
  const float* Whh1 = (const float*)d_in[3];
  const float* bih1 = (const float*)d_in[4];
  const float* bhh1 = (const float*)d_in[5];
  const float* Wih2 = (const float*)d_in[6];
  const float* Whh2 = (const float*)d_in[7];
  const float* bih2 = (const float*)d_in[8];
  const float* bhh2 = (const float*)d_in[9];
  float* out = (float*)d_out;

  lstm2_pc3_kernel<<<dim3(512), dim3(192), 0, stream>>>(
      x1, x2, Wih1, Whh1, bih1, bhh1, Wih2, Whh2, bih2, bhh2, out);
}